// Round 3
// baseline (287.490 us; speedup 1.0000x reference)
//
#include <hip/hip_runtime.h>
#include <cstdint>

// SNN (2-layer LIF, 10 timesteps) — one thread per batch element.
// Bit-exact JAX emulation (verified absmax=0 in R1/R2):
//  - threefry2x32-20, key=(0,42), partitionable counter mode, out = x0^x1
//  - spike compare in integer domain with PRE-SHIFTED thresholds:
//      u < x  <=>  (h>>9) < T  <=>  h < (T<<9)   [exact for T < 2^23;
//      T = 2^23 saturates to 0xFFFFFFFF, mismatch prob ~2^-32 per such draw]
//  - rotates = v_alignbit_b32 (1 op); key injections fused into the next
//    round's add (v_add3_u32): x0 = x0 + Kc + x1
//  - LIF elementwise ops with explicit single-rounded intrinsics
//  - dots as ascending fma chains from 0, then (i_dec + dot_in) + dot_rec

#define ROTL(x, r) __builtin_amdgcn_alignbit((x), (x), 32 - (r))
// plain quarter-round
#define QR(r) { x0 += x1; x1 = ROTL(x1, (r)); x1 ^= x0; }
// quarter-round with preceding key injection (c0 into x0 fused via add3)
#define QRI(r, c0, c1) { x1 += (c1); x0 = x0 + (c0) + x1; x1 = ROTL(x1, (r)); x1 ^= x0; }

__device__ __forceinline__ uint32_t tf_hash(uint32_t x1i) {
  // key (0,42): ks0=0, ks1=42, ks2=0x1BD11BDA^42=0x1BD11BF0
  // caller passes x1i = counter + 42 (counter + ks1); x0 init = counter? no:
  // x0 = 0 + ks0 = 0, so round 1's "x0 += x1" gives x0 = x1i.
  uint32_t x0 = x1i;                         // round 1: x0 = 0 + x1
  uint32_t x1 = (uint32_t)ROTL(x1i, 13) ^ x0;
  QR(15) QR(26) QR(6)
  QRI(17, 42u,          0x1BD11BF1u)         // inject (ks1, ks2+1), round 5
  QR(29) QR(16) QR(24)
  QRI(13, 0x1BD11BF0u,  2u)                  // inject (ks2, ks0+2), round 9
  QR(15) QR(26) QR(6)
  QRI(17, 0u,           45u)                 // inject (ks0, ks1+3), round 13
  QR(29) QR(16) QR(24)
  QRI(13, 42u,          0x1BD11BF4u)         // inject (ks1, ks2+4), round 17
  QR(15) QR(26) QR(6)
  x0 += 0x1BD11BF0u;                         // inject (ks2, ks0+5)
  x1 += 5u;
  return x0 ^ x1;
}

__global__ __launch_bounds__(256) void snn_kernel(
    const float* __restrict__ x_in, const float* __restrict__ w_in0,
    const float* __restrict__ w_rec0, const float* __restrict__ w_in1,
    const float* __restrict__ w_rec1, float* __restrict__ out, int B)
{
  int b = blockIdx.x * blockDim.x + threadIdx.x;
  if (b >= B) return;

  // ---- pre-shifted integer spike thresholds ----
  // T = ceil(x * 2^23) in [0, 2^23]; Ts = T<<9, saturated at T = 2^23.
  uint32_t Ts[12];
  {
    const float4* xv = reinterpret_cast<const float4*>(x_in + (size_t)b * 12);
    float4 q0 = xv[0], q1 = xv[1], q2 = xv[2];
    float x[12] = {q0.x,q0.y,q0.z,q0.w, q1.x,q1.y,q1.z,q1.w, q2.x,q2.y,q2.z,q2.w};
    #pragma unroll
    for (int j = 0; j < 12; ++j) {
      uint32_t T = (uint32_t)__builtin_ceilf(x[j] * 8388608.0f);
      Ts[j] = (T >= 0x800000u) ? 0xFFFFFFFFu : (T << 9);
    }
  }

  // ---- weights (wave-uniform -> scalar loads) ----
  float W0[6][12], R0[6][6], W1[6], R1;
  #pragma unroll
  for (int n = 0; n < 6; ++n) {
    #pragma unroll
    for (int j = 0; j < 12; ++j) W0[n][j] = w_in0[n * 12 + j];
  }
  #pragma unroll
  for (int n = 0; n < 6; ++n) {
    #pragma unroll
    for (int j = 0; j < 6; ++j) R0[n][j] = w_rec0[n * 6 + j];
  }
  #pragma unroll
  for (int j = 0; j < 6; ++j) W1[j] = w_in1[j];
  R1 = w_rec1[0];

  // ---- state ----
  float v0[6], i0[6], z0[6];
  #pragma unroll
  for (int n = 0; n < 6; ++n) { v0[n] = 0.0f; i0[n] = 0.0f; z0[n] = 0.0f; }
  float v1 = 0.0f, i1 = 0.0f, z1 = 0.0f;

  const uint32_t t_stride = (uint32_t)B * 12u;
  uint32_t base = (uint32_t)b * 12u + 42u;   // counter + ks1, for (t, b, 0)

  #pragma unroll
  for (int t = 0; t < 10; ++t) {
    // ---- Poisson spikes (integer-domain compare, bit-exact) ----
    float sp[12];
    #pragma unroll
    for (int j = 0; j < 12; ++j) {
      uint32_t h = tf_hash(base + (uint32_t)j);
      sp[j] = (h < Ts[j]) ? 1.0f : 0.0f;
    }
    base += t_stride;

    // ---- layer 0: 6 LIF neurons ----
    float zn[6], vn[6], inew[6];
    #pragma unroll
    for (int n = 0; n < 6; ++n) {
      float vdec = __fadd_rn(v0[n], __fmul_rn(0.1f, __fsub_rn(i0[n], v0[n])));
      float idec = __fsub_rn(i0[n], __fmul_rn(0.2f, i0[n]));
      bool fire = (vdec > 1.0f);          // == (vdec - 1.0f) > 0, exactly
      zn[n] = fire ? 1.0f : 0.0f;
      vn[n] = fire ? 0.0f : vdec;
      float d1 = 0.0f;
      #pragma unroll
      for (int j = 0; j < 12; ++j) d1 = __fmaf_rn(sp[j], W0[n][j], d1);
      float d2 = 0.0f;
      #pragma unroll
      for (int j = 0; j < 6; ++j) d2 = __fmaf_rn(z0[j], R0[n][j], d2);
      inew[n] = __fadd_rn(__fadd_rn(idec, d1), d2);
    }

    // ---- layer 1: 1 LIF neuron (input = NEW z0, recurrence = OLD z1) ----
    {
      float vdec = __fadd_rn(v1, __fmul_rn(0.1f, __fsub_rn(i1, v1)));
      float idec = __fsub_rn(i1, __fmul_rn(0.2f, i1));
      bool fire = (vdec > 1.0f);
      float z1n = fire ? 1.0f : 0.0f;
      float v1n = fire ? 0.0f : vdec;
      float d1 = 0.0f;
      #pragma unroll
      for (int j = 0; j < 6; ++j) d1 = __fmaf_rn(zn[j], W1[j], d1);
      float d2 = __fmaf_rn(z1, R1, 0.0f);  // K=1 dot
      float i1n = __fadd_rn(__fadd_rn(idec, d1), d2);
      z1 = z1n; v1 = v1n; i1 = i1n;
    }

    // ---- commit layer-0 state ----
    #pragma unroll
    for (int n = 0; n < 6; ++n) { z0[n] = zn[n]; v0[n] = vn[n]; i0[n] = inew[n]; }
  }

  out[b] = z1;  // final-timestep output spike
}

extern "C" void kernel_launch(void* const* d_in, const int* in_sizes, int n_in,
                              void* d_out, int out_size, void* d_ws, size_t ws_size,
                              hipStream_t stream) {
  const float* x      = (const float*)d_in[0];   // [B,12]
  const float* w_in0  = (const float*)d_in[1];   // [6,12]
  const float* w_rec0 = (const float*)d_in[2];   // [6,6]
  const float* w_in1  = (const float*)d_in[3];   // [1,6]
  const float* w_rec1 = (const float*)d_in[4];   // [1,1]
  float* out = (float*)d_out;                    // [B,1]

  const int B = out_size;                        // 1048576
  const int block = 256;
  const int grid = (B + block - 1) / block;
  snn_kernel<<<grid, block, 0, stream>>>(x, w_in0, w_rec0, w_in1, w_rec1, out, B);
}

// Round 4
// 285.633 us; speedup vs baseline: 1.0065x; 1.0065x over previous
//
#include <hip/hip_runtime.h>
#include <cstdint>

// SNN (2-layer LIF, 10 timesteps) — one thread per batch element.
// Bit-exact JAX emulation (verified absmax=0 in R1/R2/R3):
//  - threefry2x32-20, key=(0,42), partitionable counter mode, out = x0^x1
//  - spike compare in integer domain: u < x  <=>  (h>>9) < ceil(x*2^23)
//  - rotates = v_alignbit_b32 via builtin (R2 formulation — measured best)
//  - LIF elementwise ops with explicit single-rounded intrinsics
//  - dots as ascending fma chains from 0, then (i_dec + dot_in) + dot_rec
//
// DEAD-CODE ELIMINATION ACROSS TIME (R4): output = z1(t=9) = (v1dec(9) > 1)
// depends only on v1,i1 entering step 9. Backward trace shows:
//   * step 9: everything except the layer-1 decay+compare is discarded
//   * step 8: i0n (layer-0 dots + spikes) feeds only discarded z0n(9)
//   * hence sp(t=8), sp(t=9) are dead -> 96 hashes instead of 120
// Every surviving value is computed by the identical op sequence -> bit-exact.

#define TFR(r) { x0 += x1; x1 = __builtin_amdgcn_alignbit(x1, x1, 32 - (r)); x1 ^= x0; }

__device__ __forceinline__ uint32_t tf_hash(uint32_t c) {
  // key (0,42): ks0=0, ks1=42, ks2=0x1BD11BDA^42=0x1BD11BF0
  uint32_t x0 = 0u;
  uint32_t x1 = c + 42u;                   // c + ks1
  TFR(13) TFR(15) TFR(26) TFR(6)
  x0 += 42u;          x1 += 0x1BD11BF1u;   // ks1, ks2+1
  TFR(17) TFR(29) TFR(16) TFR(24)
  x0 += 0x1BD11BF0u;  x1 += 2u;            // ks2, ks0+2
  TFR(13) TFR(15) TFR(26) TFR(6)
  /* x0 += 0 */       x1 += 45u;           // ks0, ks1+3
  TFR(17) TFR(29) TFR(16) TFR(24)
  x0 += 42u;          x1 += 0x1BD11BF4u;   // ks1, ks2+4
  TFR(13) TFR(15) TFR(26) TFR(6)
  x0 += 0x1BD11BF0u;  x1 += 5u;            // ks2, ks0+5
  return x0 ^ x1;
}

__global__ __launch_bounds__(256) void snn_kernel(
    const float* __restrict__ x_in, const float* __restrict__ w_in0,
    const float* __restrict__ w_rec0, const float* __restrict__ w_in1,
    const float* __restrict__ w_rec1, float* __restrict__ out, int B)
{
  int b = blockIdx.x * blockDim.x + threadIdx.x;
  if (b >= B) return;

  // ---- integer spike thresholds: T[j] = ceil(x[j] * 2^23), exact ----
  uint32_t T[12];
  {
    const float4* xv = reinterpret_cast<const float4*>(x_in + (size_t)b * 12);
    float4 q0 = xv[0], q1 = xv[1], q2 = xv[2];
    float x[12] = {q0.x,q0.y,q0.z,q0.w, q1.x,q1.y,q1.z,q1.w, q2.x,q2.y,q2.z,q2.w};
    #pragma unroll
    for (int j = 0; j < 12; ++j)
      T[j] = (uint32_t)__builtin_ceilf(x[j] * 8388608.0f);
  }

  // ---- weights (wave-uniform -> scalar loads) ----
  float W0[6][12], R0[6][6], W1[6], R1;
  #pragma unroll
  for (int n = 0; n < 6; ++n) {
    #pragma unroll
    for (int j = 0; j < 12; ++j) W0[n][j] = w_in0[n * 12 + j];
  }
  #pragma unroll
  for (int n = 0; n < 6; ++n) {
    #pragma unroll
    for (int j = 0; j < 6; ++j) R0[n][j] = w_rec0[n * 6 + j];
  }
  #pragma unroll
  for (int j = 0; j < 6; ++j) W1[j] = w_in1[j];
  R1 = w_rec1[0];

  // ---- state ----
  float v0[6], i0[6], z0[6];
  #pragma unroll
  for (int n = 0; n < 6; ++n) { v0[n] = 0.0f; i0[n] = 0.0f; z0[n] = 0.0f; }
  float v1 = 0.0f, i1 = 0.0f, z1 = 0.0f;

  const uint32_t t_stride = (uint32_t)B * 12u;
  uint32_t base = (uint32_t)b * 12u;   // counter for (t, b, 0); += t_stride per step

  // ---- steps 0..7: full computation ----
  #pragma unroll
  for (int t = 0; t < 8; ++t) {
    // Poisson spikes (integer-domain compare, bit-exact)
    float sp[12];
    #pragma unroll
    for (int j = 0; j < 12; ++j) {
      uint32_t h = tf_hash(base + (uint32_t)j);
      sp[j] = ((h >> 9) < T[j]) ? 1.0f : 0.0f;
    }
    base += t_stride;

    // layer 0: 6 LIF neurons
    float zn[6], vn[6], inew[6];
    #pragma unroll
    for (int n = 0; n < 6; ++n) {
      float vdec = __fadd_rn(v0[n], __fmul_rn(0.1f, __fsub_rn(i0[n], v0[n])));
      float idec = __fsub_rn(i0[n], __fmul_rn(0.2f, i0[n]));
      bool fire = (vdec > 1.0f);          // == (vdec - 1.0f) > 0, exactly
      zn[n] = fire ? 1.0f : 0.0f;
      vn[n] = fire ? 0.0f : vdec;
      float d1 = 0.0f;
      #pragma unroll
      for (int j = 0; j < 12; ++j) d1 = __fmaf_rn(sp[j], W0[n][j], d1);
      float d2 = 0.0f;
      #pragma unroll
      for (int j = 0; j < 6; ++j) d2 = __fmaf_rn(z0[j], R0[n][j], d2);
      inew[n] = __fadd_rn(__fadd_rn(idec, d1), d2);
    }

    // layer 1: 1 LIF neuron (input = NEW z0, recurrence = OLD z1)
    {
      float vdec = __fadd_rn(v1, __fmul_rn(0.1f, __fsub_rn(i1, v1)));
      float idec = __fsub_rn(i1, __fmul_rn(0.2f, i1));
      bool fire = (vdec > 1.0f);
      float z1n = fire ? 1.0f : 0.0f;
      float v1n = fire ? 0.0f : vdec;
      float d1 = 0.0f;
      #pragma unroll
      for (int j = 0; j < 6; ++j) d1 = __fmaf_rn(zn[j], W1[j], d1);
      float d2 = __fmaf_rn(z1, R1, 0.0f);  // K=1 dot
      float i1n = __fadd_rn(__fadd_rn(idec, d1), d2);
      z1 = z1n; v1 = v1n; i1 = i1n;
    }

    // commit layer-0 state
    #pragma unroll
    for (int n = 0; n < 6; ++n) { z0[n] = zn[n]; v0[n] = vn[n]; i0[n] = inew[n]; }
  }

  // ---- step 8 (reduced): layer-0 spikes only; layer-1 full v/i update ----
  float i1_9, v1_9;
  {
    float zn8[6];
    #pragma unroll
    for (int n = 0; n < 6; ++n) {
      float vdec = __fadd_rn(v0[n], __fmul_rn(0.1f, __fsub_rn(i0[n], v0[n])));
      zn8[n] = (vdec > 1.0f) ? 1.0f : 0.0f;
      // i0n(8), v0n(8) feed only discarded state -> skipped
    }
    float vdec = __fadd_rn(v1, __fmul_rn(0.1f, __fsub_rn(i1, v1)));
    float idec = __fsub_rn(i1, __fmul_rn(0.2f, i1));
    bool fire = (vdec > 1.0f);
    v1_9 = fire ? 0.0f : vdec;
    float d1 = 0.0f;
    #pragma unroll
    for (int j = 0; j < 6; ++j) d1 = __fmaf_rn(zn8[j], W1[j], d1);
    float d2 = __fmaf_rn(z1, R1, 0.0f);
    i1_9 = __fadd_rn(__fadd_rn(idec, d1), d2);
  }

  // ---- step 9 (reduced): output spike only ----
  float vdec9 = __fadd_rn(v1_9, __fmul_rn(0.1f, __fsub_rn(i1_9, v1_9)));
  out[b] = (vdec9 > 1.0f) ? 1.0f : 0.0f;
}

extern "C" void kernel_launch(void* const* d_in, const int* in_sizes, int n_in,
                              void* d_out, int out_size, void* d_ws, size_t ws_size,
                              hipStream_t stream) {
  const float* x      = (const float*)d_in[0];   // [B,12]
  const float* w_in0  = (const float*)d_in[1];   // [6,12]
  const float* w_rec0 = (const float*)d_in[2];   // [6,6]
  const float* w_in1  = (const float*)d_in[3];   // [1,6]
  const float* w_rec1 = (const float*)d_in[4];   // [1,1]
  float* out = (float*)d_out;                    // [B,1]

  const int B = out_size;                        // 1048576
  const int block = 256;
  const int grid = (B + block - 1) / block;
  snn_kernel<<<grid, block, 0, stream>>>(x, w_in0, w_rec0, w_in1, w_rec1, out, B);
}